// Round 1
// 144.100 us; speedup vs baseline: 1.0342x; 1.0342x over previous
//
#include <hip/hip_runtime.h>

#define BB 4
#define NN 1024
#define KK 9
#define C  32
#define CM 128
#define M  (BB*NN)       // 4096 rows
#define EPSB 1e-5f
#define SLOPE 0.01f

#define KPAD 296              // padded row stride (f16) for comp_w / kmat tiles
#define CHUNK_F16 (32*KPAD)   // 9472 f16 per (b,s) comp_w tile (32 n-rows)
#define CHUNK_F4  (CHUNK_F16/8) // 1184 float4 per tile

typedef _Float16 f16x8 __attribute__((ext_vector_type(8)));
typedef _Float16 f16x4 __attribute__((ext_vector_type(4)));
typedef float    f32x4 __attribute__((ext_vector_type(4)));

__device__ __forceinline__ float leaky(float x){ return x > 0.f ? x : SLOPE*x; }

__device__ __forceinline__ float fexp2(float x){
#if __has_builtin(__builtin_amdgcn_exp2f)
  return __builtin_amdgcn_exp2f(x);
#else
  return exp2f(x);
#endif
}

// ---------------------------------------------------------------------------
// K1: comp_w tiles cwh[(b*32+s)*CHUNK_F16 ...] (f16, row stride KPAD)
//      tile layout [c][k*32+nl] = sum_c' w[row][c'] * conv_w[k][c'][c],
//      row = (b*32+s)*32+nl
// grid 384 = (b,s) x kt(3 k's each); thread = (nl 32) x (dq 8: 4 d each)
// Block 0 also zeroes the stats buffer (replaces hipMemsetAsync).
// ---------------------------------------------------------------------------
__global__ __launch_bounds__(256) void k1_compw(const float* __restrict__ w,
                                                const float* __restrict__ conv_w,
                                                _Float16* __restrict__ cwh,
                                                float* __restrict__ stats){
  __shared__ float cwl[3*C*C];   // 12 KB: conv_w k-slice
  int bid = blockIdx.x;
  int kt  = bid % 3;
  int s   = (bid/3) & 31, b = bid/96;
  int tid = threadIdx.x;
  if (bid == 0){ for (int i = tid; i < 320; i += 256) stats[i] = 0.f; }

  const float4* cs = (const float4*)(conv_w + kt*3*C*C);
  float4* cd = (float4*)cwl;
  for (int v = tid; v < 768; v += 256) cd[v] = cs[v];

  int nl = tid & 31, dq = tid >> 5;
  int row = (b*32 + s)*32 + nl;
  float wreg[32];
  const float4* wr = (const float4*)(w + (size_t)row*C);
  #pragma unroll
  for (int j = 0; j < 8; ++j){
    float4 t = wr[j];
    wreg[4*j]=t.x; wreg[4*j+1]=t.y; wreg[4*j+2]=t.z; wreg[4*j+3]=t.w;
  }
  __syncthreads();

  _Float16* outb = cwh + (size_t)(b*32 + s)*CHUNK_F16;
  const float4* cv = (const float4*)cwl;
  #pragma unroll
  for (int kl = 0; kl < 3; ++kl){
    float a0=0.f, a1=0.f, a2=0.f, a3=0.f;
    #pragma unroll
    for (int c = 0; c < C; ++c){
      float4 t = cv[kl*256 + c*8 + dq];   // conv_w[kt*3+kl][c][dq*4..+3], broadcast
      a0 += wreg[c]*t.x; a1 += wreg[c]*t.y; a2 += wreg[c]*t.z; a3 += wreg[c]*t.w;
    }
    int k = kt*3 + kl;
    outb[(dq*4+0)*KPAD + k*32 + nl] = (_Float16)a0;
    outb[(dq*4+1)*KPAD + k*32 + nl] = (_Float16)a1;
    outb[(dq*4+2)*KPAD + k*32 + nl] = (_Float16)a2;
    outb[(dq*4+3)*KPAD + k*32 + nl] = (_Float16)a3;
  }
}

// ---------------------------------------------------------------------------
// K2': full-row flash MFMA. Block = (b, it: 16-i tile), 512 thr (8 waves).
// Wave w: c-half = w&1, k-slice subset q=w>>1 -> ks in {q, q+4, q+8<9}.
// Per sub-chunk s (32 n): double-buffered global_load_lds stage of comp_w
// tile, VALU-gen kmat tile into other buffer, 1 barrier per iter.
// Block covers ALL 1024 n -> writes final z = leaky(sum) + BN stats.
// Eliminates the old part[] buffer and the K3 reduction kernel.
// ---------------------------------------------------------------------------
__global__ __launch_bounds__(512, 2) void k2_full(const float* __restrict__ pos,
                                                  const float* __restrict__ kpos,
                                                  const _Float16* __restrict__ cwh,
                                                  float* __restrict__ z,
                                                  float* __restrict__ stats){
  __shared__ __align__(16) _Float16 cwt[2][32*KPAD];  // 37888 B (double-buffered)
  __shared__ __align__(16) _Float16 kmt[2][16*KPAD];  // 18944 B (double-buffered)
  __shared__ __align__(16) float pnl[NN*2];           // 8192 B: all positions of batch b
  // epilogue scratch overlays cwt (dead after the main loop):
  float* red  = (float*)&cwt[0][0];   // 8*256 floats: per-wave partial tiles
  float* red2 = (float*)&cwt[1][0];   // 32*17 floats: z values for stats reduce

  int bid = blockIdx.x;
  int b = bid >> 6, it = bid & 63;
  int tid = threadIdx.x;
  int lane = tid & 63, wid = tid >> 6;
  int mm = lane & 15, quad = lane >> 4;
  int c0 = (wid & 1) * 16, q = wid >> 1;
  int ig = tid >> 5, nl = tid & 31;

  const float BETA = -0.72134752f;  // -0.5 * log2(e)
  float Ak[KK], Bk[KK], Ck[KK];
  #pragma unroll
  for (int k = 0; k < KK; ++k){
    float kxx = kpos[2*k], kyy = kpos[2*k+1];
    Ak[k] = -2.f*BETA*kxx;
    Bk[k] = -2.f*BETA*kyy;
    Ck[k] = BETA*(kxx*kxx + kyy*kyy);
  }

  // async global->LDS stage of one comp_w tile (layout matches global exactly)
#define STAGE(dstbuf, ss) do{ \
    const float4* s4_ = (const float4*)(cwh + (size_t)(b*32 + (ss))*CHUNK_F16); \
    _Pragma("unroll") \
    for (int rr_ = 0; rr_ < 3; ++rr_){ \
      int v_ = tid + rr_*512; \
      if (v_ < CHUNK_F4) \
        __builtin_amdgcn_global_load_lds( \
          (const __attribute__((address_space(1))) unsigned int*)(s4_ + v_), \
          (__attribute__((address_space(3))) unsigned int*)((dstbuf) + (size_t)(rr_*512 + wid*64)*8), \
          16, 0, 0); \
    } \
  }while(0)

  // kmat tile gen: thread (ig,nl) does 9 exps via exp2 with folded constants
#define GEN(dstbuf, ss) do{ \
    float dx_ = pix - pnl[2*((ss)*32 + nl)]; \
    float dy_ = piy - pnl[2*((ss)*32 + nl) + 1]; \
    float e0_ = BETA*(dx_*dx_ + dy_*dy_); \
    _Float16* kr_ = (dstbuf) + ig*KPAD + nl; \
    _Pragma("unroll") \
    for (int k = 0; k < KK; ++k){ \
      float t_ = (e0_ + Ck[k]) + dx_*Ak[k] + dy_*Bk[k]; \
      kr_[k*32] = (_Float16)fexp2(t_); \
    } \
  }while(0)

  // prologue: positions + tile 0
  ((float4*)pnl)[tid] = ((const float4*)(pos + (size_t)b*NN*2))[tid];
  STAGE(cwt[0], 0);
  __syncthreads();
  float pix = pnl[2*(it*16 + ig)];
  float piy = pnl[2*(it*16 + ig) + 1];
  GEN(kmt[0], 0);
  __syncthreads();

  f32x4 acc = {0.f,0.f,0.f,0.f};
  for (int s = 0; s < 32; ++s){
    int cur = s & 1, nxt = cur ^ 1;
    if (s < 31) STAGE(cwt[nxt], s+1);      // loads in flight across MFMA+gen
    #pragma unroll
    for (int t = 0; t < 3; ++t){
      int ks = q + t*4;
      if (ks < KK){                         // wave-uniform; only t=2 ever skips
        f16x8 a  = *(const f16x8*)&kmt[cur][mm*KPAD + ks*32 + quad*8];
        f16x8 bf = *(const f16x8*)&cwt[cur][(c0+mm)*KPAD + ks*32 + quad*8];
        acc = __builtin_amdgcn_mfma_f32_16x16x32_f16(a, bf, acc, 0, 0, 0);
      }
    }
    if (s < 31) GEN(kmt[nxt], s+1);
    __syncthreads();                        // one barrier per sub-chunk
  }
#undef STAGE
#undef GEN

  // cross-wave reduce of the 4 k-subset partials per c-half
  float* rp = red + wid*256;
  #pragma unroll
  for (int r = 0; r < 4; ++r) rp[(quad*4 + r)*16 + mm] = acc[r];
  __syncthreads();
  {
    int r = tid >> 5, c = tid & 31;
    int half = c >> 4, cc = c & 15;
    int o = r*16 + cc;
    float v = red[half*256 + o] + red[(2+half)*256 + o]
            + red[(4+half)*256 + o] + red[(6+half)*256 + o];
    v = leaky(v);
    z[((size_t)b*NN + it*16 + r)*C + c] = v;   // 512 consecutive floats
    red2[c*17 + r] = v;
  }
  __syncthreads();
  if (tid < C){
    float s1 = 0.f, s2 = 0.f;
    #pragma unroll
    for (int r = 0; r < 16; ++r){ float t = red2[tid*17 + r]; s1 += t; s2 += t*t; }
    atomicAdd(&stats[tid], s1);
    atomicAdd(&stats[C + tid], s2);
  }
}

// ---------------------------------------------------------------------------
// K4: y = bn(z)+weights ; h = leaky(y@w1+b1) ; stats for h (stats[64..319])
// ---------------------------------------------------------------------------
__global__ __launch_bounds__(256) void k4_mlp1(const float* __restrict__ z,
                                               const float* __restrict__ weights,
                                               const float* __restrict__ bn_g,
                                               const float* __restrict__ bn_b,
                                               const float* __restrict__ w1,
                                               const float* __restrict__ b1,
                                               float* __restrict__ stats,
                                               float* __restrict__ y,
                                               float* __restrict__ h){
  __shared__ float w1l[C*CM];   // 16 KB
  __shared__ float yl[16*C];
  __shared__ float lt1[CM], lt2[CM];
  int tid = threadIdx.x;
  int row0 = blockIdx.x * 16;
  for (int i = tid; i < C*CM; i += 256) w1l[i] = w1[i];
  if (tid < CM){ lt1[tid]=0.f; lt2[tid]=0.f; }
  #pragma unroll
  for (int j = 0; j < 2; ++j){
    int e = tid + j*256;
    int c  = e & (C-1);
    int rl = e >> 5;
    float s1 = stats[c], s2 = stats[C + c];
    float mean = s1 * (1.f/M);
    float var  = s2 * (1.f/M) - mean*mean;
    float sc = bn_g[c] * rsqrtf(var + EPSB);
    float sh = bn_b[c] - mean*sc;
    int row = row0 + rl;
    float v = z[(size_t)row*C + c]*sc + sh + weights[(size_t)row*C + c];
    yl[e] = v;
    y[(size_t)row*C + c] = v;
  }
  __syncthreads();
  #pragma unroll
  for (int j = 0; j < 8; ++j){
    int e = tid + j*256;
    int col = e & (CM-1);
    int rl  = e >> 7;
    float acc = b1[col];
    #pragma unroll
    for (int c = 0; c < C; ++c) acc += yl[rl*C + c] * w1l[c*CM + col];
    acc = leaky(acc);
    h[(size_t)(row0+rl)*CM + col] = acc;
    atomicAdd(&lt1[col], acc);
    atomicAdd(&lt2[col], acc*acc);
  }
  __syncthreads();
  if (tid < CM){
    atomicAdd(&stats[2*C + tid],      lt1[tid]);
    atomicAdd(&stats[2*C + CM + tid], lt2[tid]);
  }
}

// ---------------------------------------------------------------------------
// K5: out = y + (bn1(h) @ w2 + b2)
// ---------------------------------------------------------------------------
__global__ __launch_bounds__(256) void k5_mlp2(const float* __restrict__ h,
                                               const float* __restrict__ y,
                                               const float* __restrict__ bn1_g,
                                               const float* __restrict__ bn1_b,
                                               const float* __restrict__ w2,
                                               const float* __restrict__ b2,
                                               const float* __restrict__ stats,
                                               float* __restrict__ out){
  __shared__ float w2l[CM*C];   // 16 KB
  __shared__ float hl[16*CM];   // 8 KB
  int tid = threadIdx.x;
  int row0 = blockIdx.x * 16;
  for (int i = tid; i < CM*C; i += 256) w2l[i] = w2[i];
  #pragma unroll
  for (int j = 0; j < 8; ++j){
    int e = tid + j*256;
    int col = e & (CM-1);
    int rl  = e >> 7;
    float t1 = stats[2*C + col], t2 = stats[2*C + CM + col];
    float mean = t1*(1.f/M);
    float var  = t2*(1.f/M) - mean*mean;
    float sc = bn1_g[col]*rsqrtf(var + EPSB);
    float sh = bn1_b[col] - mean*sc;
    hl[e] = h[(size_t)(row0+rl)*CM + col]*sc + sh;
  }
  __syncthreads();
  #pragma unroll
  for (int j = 0; j < 2; ++j){
    int e = tid + j*256;
    int c  = e & (C-1);
    int rl = e >> 5;
    float acc = b2[c];
    #pragma unroll
    for (int jj = 0; jj < CM; ++jj) acc += hl[rl*CM + jj] * w2l[jj*C + c];
    int row = row0 + rl;
    out[(size_t)row*C + c] = y[(size_t)row*C + c] + acc;
  }
}

// ---------------------------------------------------------------------------
extern "C" void kernel_launch(void* const* d_in, const int* in_sizes, int n_in,
                              void* d_out, int out_size, void* d_ws, size_t ws_size,
                              hipStream_t stream) {
  const float* positions = (const float*)d_in[0];
  const float* weights   = (const float*)d_in[1];
  const float* kpos      = (const float*)d_in[2];
  const float* conv_w    = (const float*)d_in[3];
  const float* bn_g      = (const float*)d_in[4];
  const float* bn_b      = (const float*)d_in[5];
  const float* w1        = (const float*)d_in[6];
  const float* b1        = (const float*)d_in[7];
  const float* bn1_g     = (const float*)d_in[8];
  const float* bn1_b     = (const float*)d_in[9];
  const float* w2        = (const float*)d_in[10];
  const float* b2        = (const float*)d_in[11];
  float* out = (float*)d_out;

  float* ws = (float*)d_ws;
  size_t off = 0;
  _Float16* cwh = (_Float16*)(ws + off); off += (size_t)128*CHUNK_F16/2;  // 606,208 floats
  float* z     = ws + off; off += (size_t)M*C;
  float* y     = ws + off; off += (size_t)M*C;
  float* h     = ws + off; off += (size_t)M*CM;
  float* stats = ws + off; off += 320;

  k1_compw<<<384, 256, 0, stream>>>(weights, conv_w, cwh, stats);
  k2_full <<<256, 512, 0, stream>>>(positions, kpos, cwh, z, stats);
  k4_mlp1 <<<M/16, 256, 0, stream>>>(z, weights, bn_g, bn_b, w1, b1, stats, y, h);
  k5_mlp2 <<<M/16, 256, 0, stream>>>(h, y, bn1_g, bn1_b, w2, b2, stats, out);
}